// Round 1
// baseline (254.127 us; speedup 1.0000x reference)
//
#include <hip/hip_runtime.h>
#include <stdint.h>
#include <stddef.h>

// CapsuleFC: B=64, N_IN=2048, D_IN=16, N_OUT=64, D_OUT=16, num_iter=1 (ignored by ref body)
constexpr int B_ = 64, N_ = 2048, A_ = 16, M_ = 64, D_ = 16;
constexpr float SCALE_ = 0.25f;   // 1/sqrt(16)
constexpr float EPS_ = 1e-6f;

// async global->LDS, 16B per lane; LDS dest must be wave-uniform base (lane*16 added by HW)
#define GLOAD_LDS16(g, l)                                                      \
  __builtin_amdgcn_global_load_lds((__attribute__((address_space(1))) void*)(g), \
                                   (__attribute__((address_space(3))) void*)(l), \
                                   16, 0, 0)

// grid: (4 bgroups, nch chunks).  block: 256 threads = 4 waves.
// wave wv handles b in [bgroup*16 + wv*4, +4); lane l owns out-capsule m = l.
__global__ __launch_bounds__(256, 2) void caps_main(
    const float* __restrict__ input,   // [B,N,A]
    const float* __restrict__ cact,    // [B,N]
    const float* __restrict__ ncv,     // [B,M,D]
    const float* __restrict__ nact,    // [B,M]
    const float* __restrict__ w,       // [N,A,M,D]
    float* __restrict__ qk_out,        // [B,N,M]
    float* __restrict__ partial,       // [nch,B,M,D]
    int C)                             // n's per chunk
{
  __shared__ float wl[A_ * M_ * D_];   // 64 KB, one w[n] slab (physically swizzled)

  const int tid  = threadIdx.x;
  const int lane = tid & 63;
  const int wv   = __builtin_amdgcn_readfirstlane(tid >> 6);
  const int bg   = blockIdx.x;         // 0..3
  const int ch   = blockIdx.y;         // 0..nch-1
  const int b0   = bg * 16 + wv * 4;
  const int n0   = ch * C;
  const int n1   = (n0 + C < N_) ? (n0 + C) : N_;
  const int sl   = (lane >> 1) & 3;    // read-side chunk swizzle for this lane

  float na[4];
#pragma unroll
  for (int i = 0; i < 4; ++i) na[i] = nact[(b0 + i) * M_ + lane];

  float acc[4][16];
#pragma unroll
  for (int i = 0; i < 4; ++i)
#pragma unroll
    for (int d = 0; d < 16; ++d) acc[i][d] = 0.f;

  for (int n = n0; n < n1; ++n) {
    __syncthreads();  // previous iteration's LDS reads done before overwrite
    {
      const char* wsrc = (const char*)(w + (size_t)n * (A_ * M_ * D_));
#pragma unroll
      for (int i = 0; i < 16; ++i) {
        // physical LDS byte this thread fills; fetch the logical byte that belongs there.
        const uint32_t P = (uint32_t)(i * 4096 + tid * 16);
        const uint32_t S = P ^ (((P >> 7) & 3u) << 4);  // involution on bits [5:4] keyed by (l>>1)&3
        GLOAD_LDS16(wsrc + S, (char*)wl + i * 4096 + wv * 1024);
      }
    }
    __syncthreads();  // emits vmcnt(0) drain: staging complete

    // votes for 4 batches, lane's m=l, all 16 d, f32
    float v[4][16];
#pragma unroll
    for (int i = 0; i < 4; ++i)
#pragma unroll
      for (int d = 0; d < 16; ++d) v[i][d] = 0.f;

#pragma unroll
    for (int a0 = 0; a0 < 16; a0 += 2) {
      float4 wr0[4], wr1[4];
#pragma unroll
      for (int j = 0; j < 4; ++j) {
        wr0[j] = *(const float4*)((const char*)wl + (a0 + 0) * 4096 + lane * 64 + ((j ^ sl) << 4));
        wr1[j] = *(const float4*)((const char*)wl + (a0 + 1) * 4096 + lane * 64 + ((j ^ sl) << 4));
      }
#pragma unroll
      for (int bi = 0; bi < 4; ++bi) {
        const float2 ib = *(const float2*)(input + ((size_t)(b0 + bi) * N_ + n) * A_ + a0);
#pragma unroll
        for (int j = 0; j < 4; ++j) {
          v[bi][4 * j + 0] += ib.x * wr0[j].x; v[bi][4 * j + 0] += ib.y * wr1[j].x;
          v[bi][4 * j + 1] += ib.x * wr0[j].y; v[bi][4 * j + 1] += ib.y * wr1[j].y;
          v[bi][4 * j + 2] += ib.x * wr0[j].z; v[bi][4 * j + 2] += ib.y * wr1[j].z;
          v[bi][4 * j + 3] += ib.x * wr0[j].w; v[bi][4 * j + 3] += ib.y * wr1[j].w;
        }
      }
    }

    // per-b: score -> wave-local softmax -> qk -> accumulate combine
#pragma unroll
    for (int bi = 0; bi < 4; ++bi) {
      const float4* np4 = (const float4*)(ncv + ((size_t)(b0 + bi) * M_ + lane) * D_);
      const float4 c0 = np4[0], c1 = np4[1], c2 = np4[2], c3 = np4[3];
      float s = v[bi][0] * c0.x + v[bi][1] * c0.y + v[bi][2] * c0.z + v[bi][3] * c0.w
              + v[bi][4] * c1.x + v[bi][5] * c1.y + v[bi][6] * c1.z + v[bi][7] * c1.w
              + v[bi][8] * c2.x + v[bi][9] * c2.y + v[bi][10] * c2.z + v[bi][11] * c2.w
              + v[bi][12] * c3.x + v[bi][13] * c3.y + v[bi][14] * c3.z + v[bi][15] * c3.w;
      s *= SCALE_;

      float mx = s;
#pragma unroll
      for (int off = 32; off >= 1; off >>= 1) mx = fmaxf(mx, __shfl_xor(mx, off, 64));
      const float e = __expf(s - mx);
      const float ena = e * na[bi];
      float Es = e, Ps = ena;
#pragma unroll
      for (int off = 32; off >= 1; off >>= 1) {
        Es += __shfl_xor(Es, off, 64);
        Ps += __shfl_xor(Ps, off, 64);
      }
      // softmax -> *next_act -> renorm:  qk = e*na / (sum(e*na) + 1e-10*sum(e))
      const float qk = ena / (Ps + 1e-10f * Es);
      qk_out[((size_t)(b0 + bi) * N_ + n) * M_ + lane] = qk;

      float a_bn = cact[(size_t)(b0 + bi) * N_ + n];
      a_bn = fminf(fmaxf(a_bn, EPS_), 1.0f - EPS_);
      const float wq = qk * a_bn;
#pragma unroll
      for (int d = 0; d < 16; ++d) acc[bi][d] += wq * v[bi][d];
    }
  }

  // partial[ch][b][m][d]
#pragma unroll
  for (int bi = 0; bi < 4; ++bi) {
    float4* pp = (float4*)(partial + (((size_t)ch * B_ + (b0 + bi)) * M_ + lane) * D_);
#pragma unroll
    for (int j = 0; j < 4; ++j)
      pp[j] = make_float4(acc[bi][4 * j + 0], acc[bi][4 * j + 1],
                          acc[bi][4 * j + 2], acc[bi][4 * j + 3]);
  }
}

__global__ void caps_reduce(const float* __restrict__ part,
                            const float* __restrict__ nain,
                            float* __restrict__ out, int nch)
{
  const int i = blockIdx.x * 256 + threadIdx.x;  // 65536 threads, one per out[b,m,d]
  float s = 0.f;
  for (int c = 0; c < nch; ++c) s += part[(size_t)c * (B_ * M_ * D_) + i];
  out[i] = s;
  if (i < B_ * M_) out[B_ * M_ * D_ + i] = nain[i];  // next_act passthrough
}

extern "C" void kernel_launch(void* const* d_in, const int* in_sizes, int n_in,
                              void* d_out, int out_size, void* d_ws, size_t ws_size,
                              hipStream_t stream)
{
  const float* input = (const float*)d_in[0];
  const float* cact  = (const float*)d_in[1];
  const float* ncv   = (const float*)d_in[2];
  const float* nact  = (const float*)d_in[3];
  const float* w     = (const float*)d_in[4];

  float* out     = (float*)d_out;
  float* qk_out  = out + (B_ * M_ * D_) + (B_ * M_);   // after out and next_act
  float* partial = (float*)d_ws;

  int nch = 128;  // power of two so C divides N_ exactly
  while ((size_t)nch * (size_t)(B_ * M_ * D_) * sizeof(float) > ws_size && nch > 1) nch >>= 1;
  const int C = N_ / nch;

  hipLaunchKernelGGL(caps_main, dim3(4, nch), dim3(256), 0, stream,
                     input, cact, ncv, nact, w, qk_out, partial, C);
  hipLaunchKernelGGL(caps_reduce, dim3(B_ * M_ * D_ / 256), dim3(256), 0, stream,
                     partial, nact, out, nch);
}